// Round 7
// baseline (93.107 us; speedup 1.0000x reference)
//
#include <hip/hip_runtime.h>

// S4D kernel: K[h,l] = 2 * Re( sum_n Ct[h,n] * z[h,n]^l )
//   z  = exp(dtA),  dtA = (-exp(log_A_real) + i*A_imag) * exp(log_dt[h])
//   Ct = (C_real + i*C_imag) * (z - 1) / A
//
// R7: n-split ACROSS BLOCKS (grid = 2H, 256 thr). Block (h, half) owns
// n in [16*half, 16*half+16); partner blocks combine via atomicAdd into
// d_out zeroed by hipMemsetAsync (2 RMW per word, device-scope = cross-XCD
// safe). Swizzle h = bx & 1023, half = bx >> 10 so partners share an XCD
// slot (bx and bx+1024 -> same XCD under round-robin) for L2 locality.
//  - halves per-thread work, keeps total LDS traffic flat, and halves the
//    live register set vs R6 -> target <=64 VGPR for 8 waves/EU
//    (32 waves/CU, HW max; R5 ran at 16).
//  - LDS factor tables (zero per-(t,n) transcendentals), now pair-packed:
//      T0P[p][k] = {z_{2p}^k, z_{2p+1}^k}            (k = t & 15)
//      U1[n][m]  = {Ct z^(16m), Ct z^(16m+256)}      (m = t >> 4)
//      ABP[p]    = {2Re(w) x2, -|w|^2 x2}, w = z^256
//    -> 28 b128-class LDS reads/thread (R5: 96 mixed).
//  - scalar ping-pong 2nd-order recurrence (v_pk has no cycle advantage on
//    CDNA4; scalar halves acc registers): x_{j+1} = 2Re(w) x_j - |w|^2 x_{j-1}.
//  - block-uniform adaptive j-cutoff + per-thread decay skip (TOL=1e-3 per
//    half-block; total err ~3e-3 vs 3.9e-2 threshold). Skipped terms are
//    simply not atomically added (out already zero).

#define LLEN  4096
#define BLK   256
#define CL    16            // j per thread
#define NB    16            // n's per block
#define NPB   8             // n-pairs per block
#define TOL   1e-3f

typedef float v2f __attribute__((ext_vector_type(2)));

__global__ __launch_bounds__(BLK, 8) void s4d_kernel(
    const float* __restrict__ log_dt,
    const float* __restrict__ C_real,
    const float* __restrict__ C_imag,
    const float* __restrict__ log_A_real,
    const float* __restrict__ A_imag,
    float* __restrict__ out)
{
    const int bx    = blockIdx.x;
    const int h     = bx & 1023;
    const int half  = bx >> 10;
    const int nbase = half * NB;
    const int t     = threadIdx.x;

    __shared__ float4 sT0P[NPB][16];  // {re,im of z_{2p}^k, re,im of z_{2p+1}^k}
    __shared__ float4 sU1[NB][16];    // {Ct z^(16m)}, {Ct z^(16m+256)}
    __shared__ float4 sABP[NPB];      // {2a(e0), 2a(e1), -r2(e0), -r2(e1)}
    __shared__ v2f    sCt[NB], sW[NB];
    __shared__ float  sDrl2[NB];      // Re(dtA)*log2(e)
    __shared__ double sTrev[NB];      // step phase (revolutions)
    __shared__ float  sS, sRmax, sDrmax;
    __shared__ int    sJcut;

    // ---- stage A: per-n params, lanes 0..15 (wave 0, cold) ----
    if (t < NB) {
        const int n  = h * 32 + nbase + t;   // global (h,n) flat index
        const float dt = __expf(log_dt[h]);
        const float aR = -__expf(log_A_real[n]);
        const float aI = A_imag[n];
        const float dR = aR * dt;

        const double trev = (double)aI * (double)dt * 0.15915494309189535;

        // z = exp(dtA)
        double pz = trev; pz -= floor(pz);
        const float e1 = __expf(dR);
        const float zr = e1 * __builtin_amdgcn_cosf((float)pz);
        const float zi = e1 * __builtin_amdgcn_sinf((float)pz);

        // q = (z-1)/A ; Ct = C*q
        const float inv = 1.0f / (aR * aR + aI * aI);
        const float nr  = zr - 1.0f;
        const float qr  = (nr * aR + zi * aI) * inv;
        const float qi  = (zi * aR - nr * aI) * inv;
        const float c_r = C_real[n], c_i = C_imag[n];
        const float Ctr = c_r * qr - c_i * qi;
        const float Cti = c_r * qi + c_i * qr;

        // w = z^256
        double p256 = trev * 256.0; p256 -= floor(p256);
        const float ew = __expf(dR * 256.0f);
        const float wx = ew * __builtin_amdgcn_cosf((float)p256);
        const float wy = ew * __builtin_amdgcn_sinf((float)p256);
        const float r2 = ew * ew;
        const float drl2 = dR * 1.4426950408889634f;

        sCt[t]   = (v2f){Ctr, Cti};
        sW[t]    = (v2f){wx, wy};
        sDrl2[t] = drl2;
        sTrev[t] = trev;
        // pair-packed recurrence constants: [e] = 2Re(w), [2+e] = -|w|^2
        float* ab = (float*)&sABP[t >> 1];
        ab[t & 1]       = 2.0f * wx;
        ab[2 + (t & 1)] = -r2;

        // block bounds over this half's 16 n's
        float S  = fabsf(Ctr) + fabsf(Cti);
        float r  = ew;
        float dm = drl2;
#pragma unroll
        for (int m = 8; m >= 1; m >>= 1) {
            S  += __shfl_xor(S, m, 16);
            r   = fmaxf(r,  __shfl_xor(r,  m, 16));
            dm  = fmaxf(dm, __shfl_xor(dm, m, 16));
        }
        if (t == 0) {
            sS = S; sRmax = r; sDrmax = dm;
            int jc = CL;
            if (r < 0.9999f) {
                const float tail0 = 2.0f * S / (1.0f - r);
                jc = 0;
                float rj = 1.0f;
                while (jc < CL && tail0 * rj >= TOL) { rj *= r; ++jc; }
            }
            sJcut = jc;
        }
    }
    __syncthreads();

    // ---- stage B: factor tables, 2 passes x 256 tasks ----
    {
        // pass 1: T0 entries, task (n_local = t>>4, k = t&15)
        const int nl = t >> 4, k = t & 15;
        double p = sTrev[nl] * (double)k; p -= floor(p);
        const float g  = __builtin_amdgcn_exp2f(sDrl2[nl] * (float)k);
        const float re = g * __builtin_amdgcn_cosf((float)p);
        const float im = g * __builtin_amdgcn_sinf((float)p);
        float* dst = (float*)&sT0P[nl >> 1][k] + (nl & 1) * 2;
        dst[0] = re; dst[1] = im;

        // pass 2: U1 entries, task (n_local, m = t&15)
        const int m = k;
        double pu = sTrev[nl] * (double)(16 * m); pu -= floor(pu);
        const float gu = __builtin_amdgcn_exp2f(sDrl2[nl] * (float)(16 * m));
        const float c0 = gu * __builtin_amdgcn_cosf((float)pu);
        const float s0 = gu * __builtin_amdgcn_sinf((float)pu);
        const v2f Ct = sCt[nl];
        const v2f w  = sW[nl];
        const float u0r = Ct.x * c0 - Ct.y * s0;
        const float u0i = Ct.x * s0 + Ct.y * c0;
        const float u1r = u0r * w.x - u0i * w.y;   // u0 * w  (= +256 shift)
        const float u1i = u0r * w.y + u0i * w.x;
        sU1[nl][m] = make_float4(u0r, u0i, u1r, u1i);
    }
    __syncthreads();

    float acc[CL];
#pragma unroll
    for (int j = 0; j < CL; ++j) acc[j] = 0.0f;

    const int jcut = __builtin_amdgcn_readfirstlane(sJcut);
    bool active = (jcut > 0);
    {
        const float rmax = sRmax;
        if (rmax < 0.9999f) {
            const float bound = 2.0f * sS *
                __builtin_amdgcn_exp2f(sDrmax * (float)t) / (1.0f - rmax);
            if (bound < TOL) active = false;
        }
    }

    if (active) {
        const int t0 = t & 15, t1 = t >> 4;

        for (int ch = 0; ch < 2; ++ch) {
            float xa[8], xb[8], ca[8], cb[8];

#pragma unroll
            for (int pp = 0; pp < 4; ++pp) {
                const int pair = ch * 4 + pp;
                const float4 ab = sABP[pair];          // b128
                const float4 b  = sT0P[pair][t0];      // b128
                const float4 u0 = sU1[2 * pair][t1];   // b128
                const float4 u1 = sU1[2 * pair + 1][t1];
                const int k0 = 2 * pp, k1 = k0 + 1;
                // x0 = Re(Ct z^t), x1 = Re(Ct z^(t+256))
                xa[k0] = __builtin_fmaf(-u0.y, b.y, u0.x * b.x);
                xb[k0] = __builtin_fmaf(-u0.w, b.y, u0.z * b.x);
                xa[k1] = __builtin_fmaf(-u1.y, b.w, u1.x * b.z);
                xb[k1] = __builtin_fmaf(-u1.w, b.w, u1.z * b.z);
                ca[k0] = ab.x; ca[k1] = ab.y;
                cb[k0] = ab.z; cb[k1] = ab.w;
            }

            // j = 0, 1
#pragma unroll
            for (int k = 0; k < 8; ++k) acc[0] += xa[k];
            if (jcut > 1) {
#pragma unroll
                for (int k = 0; k < 8; ++k) acc[1] += xb[k];
            }

            // j = 2..15: scalar ping-pong (mul+fma+add per (n,j), no copies)
#pragma unroll
            for (int jp = 0; jp < (CL - 2) / 2; ++jp) {
                const int j = 2 + 2 * jp;
                if (j < jcut) {
#pragma unroll
                    for (int k = 0; k < 8; ++k) {
                        xa[k] = ca[k] * xb[k] + cb[k] * xa[k];   // x_j
                        acc[j] += xa[k];
                    }
#pragma unroll
                    for (int k = 0; k < 8; ++k) {
                        xb[k] = ca[k] * xa[k] + cb[k] * xb[k];   // x_{j+1}
                        acc[j + 1] += xb[k];
                    }
                }
            }
        }

        // combine partner halves: 2 atomics per output word (out pre-zeroed)
        float* __restrict__ o = out + (size_t)h * LLEN + t;
#pragma unroll
        for (int j = 0; j < CL; ++j)
            if (j < jcut) atomicAdd(&o[j * BLK], 2.0f * acc[j]);
    }
}

extern "C" void kernel_launch(void* const* d_in, const int* in_sizes, int n_in,
                              void* d_out, int out_size, void* d_ws, size_t ws_size,
                              hipStream_t stream) {
    const float* log_dt     = (const float*)d_in[0];
    const float* C_real     = (const float*)d_in[1];
    const float* C_imag     = (const float*)d_in[2];
    const float* log_A_real = (const float*)d_in[3];
    const float* A_imag     = (const float*)d_in[4];
    float* out = (float*)d_out;

    const int H = in_sizes[0];  // 1024
    // zero the accumulation target (harness poisons d_out to 0xAA)
    hipMemsetAsync(out, 0, (size_t)out_size * sizeof(float), stream);
    // grid = 2 blocks per h (n-halves), swizzled so partners share XCD slot
    s4d_kernel<<<dim3(2 * H), dim3(BLK), 0, stream>>>(
        log_dt, C_real, C_imag, log_A_real, A_imag, out);
}

// Round 8
// 80.742 us; speedup vs baseline: 1.1531x; 1.1531x over previous
//
#include <hip/hip_runtime.h>

// S4D kernel: K[h,l] = 2 * Re( sum_n Ct[h,n] * z[h,n]^l )
//   z  = exp(dtA),  dtA = (-exp(log_A_real) + i*A_imag) * exp(log_dt[h])
//   Ct = (C_real + i*C_imag) * (z - 1) / A
//
// R8: j-SPLIT ACROSS 2048 BLOCKS (h = bx>>1, half = bx&1), 256 thr.
// Block (h, half) computes j in [8*half, 8*half+8) for all 32 n -> outputs
// DISJOINT (no atomics, no memset; blocks fully beyond jcut store zeros and
// exit before table build). Rationale (R5 post-mortem): R5 is imbalance/
// TLP-bound, not pipe-bound - jcut spans 1..16 (10x work spread) and grid
// 1024 = exactly 4 blocks/CU with no slack. Halving the work quantum +
// 2048-block pool + ~55 live VGPR (acc[8] + 32 chain regs) re-balances and
// lets heavy CUs host up to 8 blocks.
//  - LDS factor tables (zero per-(t,n) transcendentals), pair-packed b128:
//      T0P[p][k] = {z_{2p}^k, z_{2p+1}^k}              (k = t & 15)
//      U1[n][m]  = {u0, u0*w}, u0 = Ct z^(16m+2048*half)  (m = t >> 4)
//      ABP[p]    = {2Re(w) x2, -|w|^2 x2},  w = z^256
//    start: x_{JOFF} = Re(U1.lo*T0), x_{JOFF+1} = Re(U1.hi*T0).
//  - scalar ping-pong 2nd-order recurrence x_{j+1} = 2Re(w) x_j - |w|^2 x_{j-1}
//    (v_pk has no cycle advantage on CDNA4; scalar halves registers).
//  - block-uniform adaptive j-cutoff + per-thread decay skip with the r^8
//    half-offset folded in: bound = 2S*exp2(drmax*(t+2048*half))/(1-r).

#define LLEN  4096
#define BLK   256
#define N2    32
#define NPR   16            // n-pairs
#define JPB   8             // j per block
#define TOL   1e-3f

typedef float v2f __attribute__((ext_vector_type(2)));

__global__ __launch_bounds__(BLK, 6) void s4d_kernel(
    const float* __restrict__ log_dt,
    const float* __restrict__ C_real,
    const float* __restrict__ C_imag,
    const float* __restrict__ log_A_real,
    const float* __restrict__ A_imag,
    float* __restrict__ out)
{
    const int bx   = blockIdx.x;
    const int h    = bx >> 1;
    const int half = bx & 1;
    const int joff = half * JPB;
    const int t    = threadIdx.x;

    __shared__ float4 sT0P[NPR][16];  // {re,im z_{2p}^k, re,im z_{2p+1}^k}
    __shared__ float4 sU1[N2][16];    // {Ct z^(16m+2048*half)} , {... * z^256}
    __shared__ float4 sABP[NPR];      // {2a(e0), 2a(e1), -r2(e0), -r2(e1)}
    __shared__ v2f    sCt[N2], sW[N2];
    __shared__ float  sDrl2[N2];      // Re(dtA)*log2(e)
    __shared__ double sTrev[N2];      // step phase (revolutions)
    __shared__ float  sS, sRmax, sDrmax;
    __shared__ int    sJcut;

    // ---- stage A: per-(h,n) params, lanes 0..31 (wave 0, cold) ----
    if (t < N2) {
        const int n = t;
        const float dt = __expf(log_dt[h]);
        const float aR = -__expf(log_A_real[h * N2 + n]);
        const float aI = A_imag[h * N2 + n];
        const float dR = aR * dt;

        const double trev = (double)aI * (double)dt * 0.15915494309189535;

        // z = exp(dtA)
        double pz = trev; pz -= floor(pz);
        const float e1 = __expf(dR);
        const float zr = e1 * __builtin_amdgcn_cosf((float)pz);
        const float zi = e1 * __builtin_amdgcn_sinf((float)pz);

        // q = (z-1)/A ; Ct = C*q
        const float inv = 1.0f / (aR * aR + aI * aI);
        const float nr  = zr - 1.0f;
        const float qr  = (nr * aR + zi * aI) * inv;
        const float qi  = (zi * aR - nr * aI) * inv;
        const float c_r = C_real[h * N2 + n], c_i = C_imag[h * N2 + n];
        const float Ctr = c_r * qr - c_i * qi;
        const float Cti = c_r * qi + c_i * qr;

        // w = z^256
        double p256 = trev * 256.0; p256 -= floor(p256);
        const float ew = __expf(dR * 256.0f);
        const float wx = ew * __builtin_amdgcn_cosf((float)p256);
        const float wy = ew * __builtin_amdgcn_sinf((float)p256);
        const float r2 = ew * ew;
        const float drl2 = dR * 1.4426950408889634f;

        sCt[n]   = (v2f){Ctr, Cti};
        sW[n]    = (v2f){wx, wy};
        sDrl2[n] = drl2;
        sTrev[n] = trev;
        float* ab = (float*)&sABP[n >> 1];
        ab[n & 1]       = 2.0f * wx;
        ab[2 + (n & 1)] = -r2;

        // block bounds: S >= sum|Ct|, rmax = max|w|, drmax = max drl2
        float S  = fabsf(Ctr) + fabsf(Cti);
        float r  = ew;
        float dm = drl2;
#pragma unroll
        for (int m = 16; m >= 1; m >>= 1) {
            S  += __shfl_xor(S, m, 32);
            r   = fmaxf(r,  __shfl_xor(r,  m, 32));
            dm  = fmaxf(dm, __shfl_xor(dm, m, 32));
        }
        if (n == 0) {
            sS = S; sRmax = r; sDrmax = dm;
            int jc = 16;
            if (r < 0.9999f) {
                const float tail0 = 2.0f * S / (1.0f - r);
                jc = 0;
                float rj = 1.0f;
                while (jc < 16 && tail0 * rj >= TOL) { rj *= r; ++jc; }
            }
            sJcut = jc;
        }
    }
    __syncthreads();

    const int jcut  = __builtin_amdgcn_readfirstlane(sJcut);
    const int jcl   = jcut - joff;            // local cutoff in [.., 8]
    float* __restrict__ o = out + (size_t)h * LLEN + joff * BLK + t;

    if (jcl <= 0) {
        // whole j-range beyond cutoff: store zeros, skip tables entirely
#pragma unroll
        for (int j = 0; j < JPB; ++j) o[j * BLK] = 0.0f;
        return;
    }

    // ---- stage B: factor tables, 1024 tasks / 256 threads ----
#pragma unroll
    for (int it = 0; it < 4; ++it) {
        const int tau = t + BLK * it;
        if (tau < 512) {                      // T0P (it = 0,1: uniform)
            const int n = tau >> 4, k = tau & 15;
            double p = sTrev[n] * (double)k; p -= floor(p);
            const float g = __builtin_amdgcn_exp2f(sDrl2[n] * (float)k);
            float* dst = (float*)&sT0P[n >> 1][k] + (n & 1) * 2;
            dst[0] = g * __builtin_amdgcn_cosf((float)p);
            dst[1] = g * __builtin_amdgcn_sinf((float)p);
        } else {                              // U1 (it = 2,3: uniform)
            const int tu = tau - 512;
            const int n = tu >> 4, m = tu & 15;
            const int e = 16 * m + 256 * joff;          // exponent of u0
            double pu = sTrev[n] * (double)e; pu -= floor(pu);
            const float gu = __builtin_amdgcn_exp2f(sDrl2[n] * (float)e);
            const float c0 = gu * __builtin_amdgcn_cosf((float)pu);
            const float s0 = gu * __builtin_amdgcn_sinf((float)pu);
            const v2f Ct = sCt[n];
            const v2f w  = sW[n];
            const float u0r = Ct.x * c0 - Ct.y * s0;
            const float u0i = Ct.x * s0 + Ct.y * c0;
            sU1[n][m] = make_float4(u0r, u0i,
                                    u0r * w.x - u0i * w.y,
                                    u0r * w.y + u0i * w.x);
        }
    }
    __syncthreads();

    float acc[JPB];
#pragma unroll
    for (int j = 0; j < JPB; ++j) acc[j] = 0.0f;

    bool active = true;
    {
        const float rmax = sRmax;
        if (rmax < 0.9999f) {
            // thread's total contribution here <= 2 S |z|^(t+2048 half)/(1-r)
            const float bound = 2.0f * sS *
                __builtin_amdgcn_exp2f(sDrmax * (float)(t + 2048 * half)) /
                (1.0f - rmax);
            if (bound < TOL) active = false;
        }
    }

    if (active) {
        const int t0 = t & 15, t1 = t >> 4;

        for (int ch = 0; ch < 4; ++ch) {
            float xa[8], xb[8], ca[8], cb[8];

#pragma unroll
            for (int pp = 0; pp < 4; ++pp) {
                const int pair = ch * 4 + pp;
                const float4 ab = sABP[pair];          // b128
                const float4 b  = sT0P[pair][t0];      // b128
                const float4 u0 = sU1[2 * pair][t1];   // b128 (broadcast x16)
                const float4 u1 = sU1[2 * pair + 1][t1];
                const int k0 = 2 * pp, k1 = k0 + 1;
                xa[k0] = __builtin_fmaf(-u0.y, b.y, u0.x * b.x);
                xb[k0] = __builtin_fmaf(-u0.w, b.y, u0.z * b.x);
                xa[k1] = __builtin_fmaf(-u1.y, b.w, u1.x * b.z);
                xb[k1] = __builtin_fmaf(-u1.w, b.w, u1.z * b.z);
                ca[k0] = ab.x; ca[k1] = ab.y;
                cb[k0] = ab.z; cb[k1] = ab.w;
            }

            // local j = 0, 1
#pragma unroll
            for (int k = 0; k < 8; ++k) acc[0] += xa[k];
            if (jcl > 1) {
#pragma unroll
                for (int k = 0; k < 8; ++k) acc[1] += xb[k];
            }

            // local j = 2..7: scalar ping-pong (mul+fma+add, no copies)
#pragma unroll
            for (int jp = 0; jp < (JPB - 2) / 2; ++jp) {
                const int j = 2 + 2 * jp;
                if (j < jcl) {
#pragma unroll
                    for (int k = 0; k < 8; ++k) {
                        xa[k] = ca[k] * xb[k] + cb[k] * xa[k];   // x_j
                        acc[j] += xa[k];
                    }
#pragma unroll
                    for (int k = 0; k < 8; ++k) {
                        xb[k] = ca[k] * xa[k] + cb[k] * xb[k];   // x_{j+1}
                        acc[j + 1] += xb[k];
                    }
                }
            }
        }
    }

    // disjoint coalesced stores (zeros where inactive / beyond cutoff)
#pragma unroll
    for (int j = 0; j < JPB; ++j) o[j * BLK] = 2.0f * acc[j];
}

extern "C" void kernel_launch(void* const* d_in, const int* in_sizes, int n_in,
                              void* d_out, int out_size, void* d_ws, size_t ws_size,
                              hipStream_t stream) {
    const float* log_dt     = (const float*)d_in[0];
    const float* C_real     = (const float*)d_in[1];
    const float* C_imag     = (const float*)d_in[2];
    const float* log_A_real = (const float*)d_in[3];
    const float* A_imag     = (const float*)d_in[4];
    float* out = (float*)d_out;

    const int H = in_sizes[0];  // 1024; two blocks per h (j-halves)
    s4d_kernel<<<dim3(2 * H), dim3(BLK), 0, stream>>>(
        log_dt, C_real, C_imag, log_A_real, A_imag, out);
}